// Round 12
// baseline (323.418 us; speedup 1.0000x reference)
//
#include <hip/hip_runtime.h>

#define N_NODES 100000
#define N_EDGES 400000
#define N_GRAPHS 2000
#define NODE_F 78
#define HID 128
#define PAD 32
#define SENT N_NODES   // sentinel row index (zeroed row appended to gathered buffers)

typedef __attribute__((ext_vector_type(8))) short short8v;
typedef __attribute__((ext_vector_type(4))) float f32x4;

__device__ __forceinline__ ushort f2bf(float f) {
    unsigned u = __float_as_uint(f);
    unsigned r = (u + 0x7FFFu + ((u >> 16) & 1u)) >> 16;  // round-to-nearest-even
    return (ushort)r;
}
__device__ __forceinline__ float bf2f(ushort b) {
    return __uint_as_float(((unsigned)b) << 16);
}
__device__ __forceinline__ float2 bfx2(const ushort* p) {
    unsigned u = *reinterpret_cast<const unsigned*>(p);
    return make_float2(__uint_as_float(u << 16), __uint_as_float(u & 0xffff0000u));
}
__device__ __forceinline__ unsigned packbf(float a, float b) {
    return (unsigned)f2bf(a) | ((unsigned)f2bf(b) << 16);
}
// async global->LDS, 16B per lane; lds base wave-uniform, gsrc per-lane
__device__ __forceinline__ void gload16(const ushort* g, ushort* l) {
    __builtin_amdgcn_global_load_lds((const __attribute__((address_space(1))) unsigned int*)g,
                                     (__attribute__((address_space(3))) unsigned int*)l, 16, 0, 0);
}

// ---------------- setup: zero cursor, sentinel-fill csr, zero sentinel rows ----------------

__global__ void setup_k(int* __restrict__ cursor, int4* __restrict__ csr4,
                        ushort* __restrict__ xb, ushort* __restrict__ b1,
                        ushort* __restrict__ b3) {
    int i = blockIdx.x * blockDim.x + threadIdx.x;
    if (i < N_NODES * PAD / 4) csr4[i] = make_int4(SENT, SENT, SENT, SENT);
    if (i < N_NODES) cursor[i] = 0;
    if (i < 80) xb[(size_t)N_NODES * 80 + i] = 0;
    if (i < 128) {
        b1[(size_t)N_NODES * 128 + i] = 0;
        b3[(size_t)N_NODES * 128 + i] = 0;
    }
}

__global__ void fill_csr_k(const int* __restrict__ src, const int* __restrict__ dst,
                           int* __restrict__ cursor, int* __restrict__ csr) {
    int e = blockIdx.x * blockDim.x + threadIdx.x;
    if (e >= N_EDGES) return;
    int s = src[e], d = dst[e];
    int p = atomicAdd(&cursor[d], 1);
    if (p < PAD) csr[d * PAD + p] = s;
}

__global__ void dinv_k(const int* __restrict__ deg, float* __restrict__ dinv, int n) {
    int i = blockIdx.x * blockDim.x + threadIdx.x;
    if (i < n) dinv[i] = rsqrtf((float)deg[i] + 1.0f);
}

// ---------------- x -> bf16 pre-scaled by dinv[row], padded to 80 cols ----------------

__global__ void x2bf_k(const float* __restrict__ x, const float* __restrict__ dinv,
                       ushort* __restrict__ xb) {
    int idx = blockIdx.x * blockDim.x + threadIdx.x;
    if (idx >= N_NODES * 80) return;
    int n = idx / 80, f = idx - n * 80;
    xb[idx] = (f < NODE_F) ? f2bf(x[(long long)n * NODE_F + f] * dinv[n]) : (ushort)0;
}

// ---------------- weight preps (LDS-image layouts, XOR-swizzled chunks) ----------------

// W1 [80k][128n] -> image [128n][128k] (zero-pad k>=80), chunk-swizzled
__global__ void prep_w1img_k(const float* __restrict__ W1, ushort* __restrict__ img) {
    int idx = blockIdx.x * blockDim.x + threadIdx.x;
    if (idx >= 128 * 128) return;
    int n = idx >> 7, k = idx & 127;
    int c = k >> 3;
    int slot = (c & 8) | ((c & 7) ^ (n & 7));
    img[n * 128 + slot * 8 + (k & 7)] = (k < NODE_F) ? f2bf(W1[(long long)k * 128 + n]) : (ushort)0;
}

// W2 [128k][256n] -> image: 4 quarter-tiles (64n x 128k, 16KB), chunk-swizzled
__global__ void prep_w2img_k(const float* __restrict__ W2, ushort* __restrict__ img) {
    int idx = blockIdx.x * blockDim.x + threadIdx.x;
    if (idx >= 256 * 128) return;
    int n = idx >> 7, k = idx & 127;
    int c = k >> 3;
    int slot = (c & 8) | ((c & 7) ^ (n & 7));
    img[n * 128 + slot * 8 + (k & 7)] = f2bf(W2[(long long)k * 256 + n]);
}

// W3 [256k][128n] -> image: 4 k-chunk tiles (128n x 64k, 16KB), chunk-swizzled
__global__ void prep_w3img_k(const float* __restrict__ W3, ushort* __restrict__ img) {
    int idx = blockIdx.x * blockDim.x + threadIdx.x;
    if (idx >= 128 * 256) return;
    int n = idx >> 8, k = idx & 255;
    int ch = k >> 6, cc = (k >> 3) & 7;
    img[ch * 8192 + n * 64 + ((cc ^ (n & 7)) * 8) + (k & 7)] = f2bf(W3[(long long)k * 128 + n]);
}

// ---------------- fused gather + layer-1 GEMM ----------------
// buf1 = relu( gather(xb) @ W1 + b1 ) * dinv[row], bf16.
// 512 threads = 8 waves; wave w gathers+owns rows w*16..+15. W1 image staged whole (32KB).

__global__ __launch_bounds__(512) void gemm1g_k(
        const ushort* __restrict__ Xb, const int* __restrict__ deg,
        const int* __restrict__ csr, const float* __restrict__ dinv,
        const ushort* __restrict__ W1i, const float* __restrict__ bias,
        ushort* __restrict__ C, int M) {
    __shared__ ushort At[128 * 128];   // 32KB gathered+swizzled A tile (cols 80.. zero)
    __shared__ ushort Bh[128 * 128];   // 32KB whole W1 image
    const int tid = threadIdx.x;
    const int w = tid >> 6, l = tid & 63;
    const int bm = blockIdx.x * 128;

    // issue W1 image DMA (32 chunks of 1KB; flies under the gather below)
    #pragma unroll
    for (int i = 0; i < 4; ++i) {
        int chunk = i * 8 + w;
        gload16(W1i + chunk * 512 + l * 8, &Bh[chunk * 512]);
    }

    // gather-stage A: one node per wave-iteration; lane covers cols l*2, l*2+1
    const bool act = l < 40;
    for (int t = 0; t < 16; ++t) {
        int r = w * 16 + t;
        int gr = bm + r; if (gr >= M) gr = M - 1;
        float di = dinv[gr];
        int d = deg[gr]; if (d > PAD) d = PAD;
        const int4* e4 = reinterpret_cast<const int4*>(csr + gr * PAD);
        float ax = 0.f, ay = 0.f;
        if (act) {
            float2 v = bfx2(&Xb[(size_t)gr * 80 + l * 2]);
            ax = v.x; ay = v.y;
        }
        for (int j0 = 0; j0 < d; j0 += 4) {
            int4 e = e4[j0 >> 2];
            if (act) {
                float2 v0 = bfx2(&Xb[(size_t)e.x * 80 + l * 2]);
                float2 v1 = bfx2(&Xb[(size_t)e.y * 80 + l * 2]);
                float2 v2 = bfx2(&Xb[(size_t)e.z * 80 + l * 2]);
                float2 v3 = bfx2(&Xb[(size_t)e.w * 80 + l * 2]);
                ax += v0.x + v1.x + v2.x + v3.x;
                ay += v0.y + v1.y + v2.y + v3.y;
            }
        }
        int c = l >> 2;                                   // chunk 0..15 (>=10 are zeros)
        int slot = (c & 8) | ((c & 7) ^ (r & 7));
        *reinterpret_cast<unsigned*>(&At[r * 128 + slot * 8 + (l & 3) * 2]) =
            packbf(ax * di, ay * di);
    }
    __syncthreads();   // drains gather ds_writes AND W1 DMA

    // MFMA: K=96 (chunks 0..11; 10,11 are zeros), wave owns 16 rows x 128 cols
    f32x4 acc[8];
    #pragma unroll
    for (int j = 0; j < 8; ++j) acc[j] = (f32x4){0.f, 0.f, 0.f, 0.f};
    #pragma unroll
    for (int ks = 0; ks < 3; ++ks) {
        int r = w * 16 + (l & 15);
        int ck = ks * 4 + (l >> 4);
        int sa = (ck & 8) | ((ck & 7) ^ (r & 7));
        short8v ah = *reinterpret_cast<const short8v*>(&At[r * 128 + sa * 8]);
        #pragma unroll
        for (int j = 0; j < 8; ++j) {
            int n = j * 16 + (l & 15);
            int sb = (ck & 8) | ((ck & 7) ^ (n & 7));
            short8v bh = *reinterpret_cast<const short8v*>(&Bh[n * 128 + sb * 8]);
            acc[j] = __builtin_amdgcn_mfma_f32_16x16x32_bf16(ah, bh, acc[j], 0, 0, 0);
        }
    }

    // epilogue: relu(acc+bias) * dinv[row] -> bf16 normal layout
    float dv[4];
    #pragma unroll
    for (int rg = 0; rg < 4; ++rg) {
        int gr = bm + w * 16 + (l >> 4) * 4 + rg;
        dv[rg] = (gr < M) ? dinv[gr] : 0.f;
    }
    #pragma unroll
    for (int j = 0; j < 8; ++j) {
        int gc = j * 16 + (l & 15);
        float bv = bias[gc];
        #pragma unroll
        for (int rg = 0; rg < 4; ++rg) {
            int gr = bm + w * 16 + (l >> 4) * 4 + rg;
            if (gr < M)
                C[(size_t)gr * 128 + gc] = f2bf(fmaxf(acc[j][rg] + bv, 0.0f) * dv[rg]);
        }
    }
}

// ---------------- fused gather + layer2+layer3 GEMM ----------------
// buf3 = ( relu( gather(buf1) @ W2 + b2 ) @ W3 ) * dinv[row], bf16.
// A gathered in-kernel into swizzled At; W2/W3 16KB tiles double-buffered via DMA.

__global__ __launch_bounds__(512) void gemm23g_k(
        const ushort* __restrict__ B1, const int* __restrict__ deg,
        const int* __restrict__ csr, const float* __restrict__ dinv,
        const ushort* __restrict__ W2i, const float* __restrict__ b2,
        const ushort* __restrict__ W3i, ushort* __restrict__ C, int M) {
    __shared__ ushort At[128 * 128];     // 32KB
    __shared__ ushort Wb[2][8192];       // 2x16KB
    __shared__ ushort Tb[8][1024];       // 8x2KB, per-wave
    const int tid = threadIdx.x;
    const int w = tid >> 6, l = tid & 63;
    const int bm = blockIdx.x * 128;

    // issue W2 quarter 0 DMA (flies under the gather)
    #pragma unroll
    for (int i = 0; i < 2; ++i) {
        int chunk = w * 2 + i;
        gload16(W2i + chunk * 512 + l * 8, &Wb[0][chunk * 512]);
    }

    // gather-stage A: one node per wave-iteration, all 64 lanes active (128 cols)
    for (int t = 0; t < 16; ++t) {
        int r = w * 16 + t;
        int gr = bm + r; if (gr >= M) gr = M - 1;
        float di = dinv[gr];
        int d = deg[gr]; if (d > PAD) d = PAD;
        const int4* e4 = reinterpret_cast<const int4*>(csr + gr * PAD);
        float2 v = bfx2(&B1[(size_t)gr * 128 + l * 2]);
        float ax = v.x, ay = v.y;
        for (int j0 = 0; j0 < d; j0 += 4) {
            int4 e = e4[j0 >> 2];
            float2 w0 = bfx2(&B1[(size_t)e.x * 128 + l * 2]);
            float2 w1 = bfx2(&B1[(size_t)e.y * 128 + l * 2]);
            float2 w2 = bfx2(&B1[(size_t)e.z * 128 + l * 2]);
            float2 w3 = bfx2(&B1[(size_t)e.w * 128 + l * 2]);
            ax += w0.x + w1.x + w2.x + w3.x;
            ay += w0.y + w1.y + w2.y + w3.y;
        }
        int c = l >> 2;
        int slot = (c & 8) | ((c & 7) ^ (r & 7));
        *reinterpret_cast<unsigned*>(&At[r * 128 + slot * 8 + (l & 3) * 2]) =
            packbf(ax * di, ay * di);
    }
    __syncthreads();

    f32x4 acc2[16];
    #pragma unroll
    for (int j = 0; j < 16; ++j) acc2[j] = (f32x4){0.f, 0.f, 0.f, 0.f};

    // ---- phase 1: T = A @ W2, by n-quarters (64 cols each, full K=128) ----
    #pragma unroll
    for (int q = 0; q < 4; ++q) {
        const ushort* nsrc = (q < 3) ? (W2i + (q + 1) * 8192) : W3i;
        #pragma unroll
        for (int i = 0; i < 2; ++i) {
            int chunk = w * 2 + i;
            gload16(nsrc + chunk * 512 + l * 8, &Wb[(q + 1) & 1][chunk * 512]);
        }
        const ushort* wb = Wb[q & 1];
        #pragma unroll
        for (int ks = 0; ks < 4; ++ks) {
            int r = w * 16 + (l & 15);
            int ck = ks * 4 + (l >> 4);
            int sa = (ck & 8) | ((ck & 7) ^ (r & 7));
            short8v ah = *reinterpret_cast<const short8v*>(&At[r * 128 + sa * 8]);
            #pragma unroll
            for (int jt = 0; jt < 4; ++jt) {
                int n = jt * 16 + (l & 15);
                int sb = (ck & 8) | ((ck & 7) ^ (n & 7));
                short8v bh = *reinterpret_cast<const short8v*>(&wb[n * 128 + sb * 8]);
                acc2[q * 4 + jt] = __builtin_amdgcn_mfma_f32_16x16x32_bf16(ah, bh, acc2[q * 4 + jt], 0, 0, 0);
            }
        }
        __syncthreads();
    }

    // ---- phase 2: C3 = relu(T+b2) @ W3, by k-chunks of 64; T exchange intra-wave ----
    f32x4 acc3[8];
    #pragma unroll
    for (int j = 0; j < 8; ++j) acc3[j] = (f32x4){0.f, 0.f, 0.f, 0.f};

    #pragma unroll
    for (int ch = 0; ch < 4; ++ch) {
        if (ch < 3) {
            const ushort* nsrc = W3i + (ch + 1) * 8192;
            #pragma unroll
            for (int i = 0; i < 2; ++i) {
                int chunk = w * 2 + i;
                gload16(nsrc + chunk * 512 + l * 8, &Wb[(ch + 1) & 1][chunk * 512]);
            }
        }
        #pragma unroll
        for (int jj = 0; jj < 4; ++jj) {
            int j = ch * 4 + jj;
            float bv = b2[ch * 64 + jj * 16 + (l & 15)];
            #pragma unroll
            for (int rg = 0; rg < 4; ++rg) {
                int rr = (l >> 4) * 4 + rg;
                int cl = jj * 16 + (l & 15);
                Tb[w][rr * 64 + (((cl >> 3) ^ (rr & 7)) * 8) + (cl & 7)] =
                    f2bf(fmaxf(acc2[j][rg] + bv, 0.f));
            }
        }
        const ushort* wb = Wb[ch & 1];
        #pragma unroll
        for (int ks = 0; ks < 2; ++ks) {
            int rt = l & 15;
            int ck = ks * 4 + (l >> 4);
            short8v ah = *reinterpret_cast<const short8v*>(&Tb[w][rt * 64 + ((ck ^ (rt & 7)) * 8)]);
            #pragma unroll
            for (int j3 = 0; j3 < 8; ++j3) {
                int n = j3 * 16 + (l & 15);
                short8v bh = *reinterpret_cast<const short8v*>(&wb[n * 64 + ((ck ^ (n & 7)) * 8)]);
                acc3[j3] = __builtin_amdgcn_mfma_f32_16x16x32_bf16(ah, bh, acc3[j3], 0, 0, 0);
            }
        }
        __syncthreads();
    }

    // epilogue: pre-scale by dinv[row] -> bf16 normal layout
    float dv[4];
    #pragma unroll
    for (int rg = 0; rg < 4; ++rg) {
        int gr = bm + w * 16 + (l >> 4) * 4 + rg;
        dv[rg] = (gr < M) ? dinv[gr] : 0.f;
    }
    #pragma unroll
    for (int j = 0; j < 8; ++j) {
        int gc = j * 16 + (l & 15);
        #pragma unroll
        for (int rg = 0; rg < 4; ++rg) {
            int gr = bm + w * 16 + (l >> 4) * 4 + rg;
            if (gr < M) C[(size_t)gr * 128 + gc] = f2bf(acc3[j][rg] * dv[rg]);
        }
    }
}

// ---------------- fused layer-3 gather + mean-pool + MLP head (8 waves/graph) ----------------

__global__ __launch_bounds__(512) void pool_head_k(
        const ushort* __restrict__ A,      // [N,128] bf16, pre-scaled, normal layout
        const int* __restrict__ deg, const int* __restrict__ csr,
        const float* __restrict__ dinv, const float* __restrict__ b3,
        const int* __restrict__ batch,
        const float* __restrict__ fw1, const float* __restrict__ fb1,
        const float* __restrict__ fw2, const float* __restrict__ fb2,
        float* __restrict__ out) {
    __shared__ float part[8][HID];
    __shared__ float ps[HID];
    const int g = blockIdx.x;
    const int w = threadIdx.x >> 6, lane = threadIdx.x & 63;

    int start, end;
    {
        int l = 0, h = N_NODES;
        while (l < h) { int m = (l + h) >> 1; if (batch[m] < g) l = m + 1; else h = m; }
        start = l;
        h = N_NODES;
        while (l < h) { int m = (l + h) >> 1; if (batch[m] < g + 1) l = m + 1; else h = m; }
        end = l;
    }

    float sx = 0.f, sy = 0.f;
    const float bx = b3[lane * 2], by = b3[lane * 2 + 1];
    for (int i = start + w; i < end; i += 8) {
        float di = dinv[i];
        float2 v = bfx2(&A[(size_t)i * 128 + lane * 2]);
        float ax = v.x, ay = v.y;
        int d = deg[i]; if (d > PAD) d = PAD;
        const int4* e4 = reinterpret_cast<const int4*>(csr + i * PAD);
        for (int j0 = 0; j0 < d; j0 += 4) {
            int4 e = e4[j0 >> 2];
            float2 w0 = bfx2(&A[(size_t)e.x * 128 + lane * 2]);
            float2 w1 = bfx2(&A[(size_t)e.y * 128 + lane * 2]);
            float2 w2 = bfx2(&A[(size_t)e.z * 128 + lane * 2]);
            float2 w3 = bfx2(&A[(size_t)e.w * 128 + lane * 2]);
            ax += w0.x + w1.x + w2.x + w3.x;
            ay += w0.y + w1.y + w2.y + w3.y;
        }
        sx += fmaxf(ax * di + bx, 0.f);
        sy += fmaxf(ay * di + by, 0.f);
    }
    part[w][lane * 2] = sx;
    part[w][lane * 2 + 1] = sy;
    __syncthreads();

    if (w == 0) {
        float inv = (end > start) ? 1.0f / (float)(end - start) : 0.0f;
        float s0 = 0.f, s1 = 0.f;
        #pragma unroll
        for (int q = 0; q < 8; ++q) {
            s0 += part[q][lane * 2];
            s1 += part[q][lane * 2 + 1];
        }
        ps[lane * 2] = s0 * inv;
        ps[lane * 2 + 1] = s1 * inv;
    }
    __syncthreads();

    if (w == 0) {
        float acc = fb1[lane];
        #pragma unroll 8
        for (int k = 0; k < HID; ++k) acc = fmaf(ps[k], fw1[k * 64 + lane], acc);
        float v = fmaxf(acc, 0.0f) * fw2[lane];
        #pragma unroll
        for (int off = 32; off > 0; off >>= 1) v += __shfl_down(v, off);
        if (lane == 0) out[g] = v + fb2[0];
    }
}

// ---------------- launch ----------------

extern "C" void kernel_launch(void* const* d_in, const int* in_sizes, int n_in,
                              void* d_out, int out_size, void* d_ws, size_t ws_size,
                              hipStream_t stream) {
    const float* x     = (const float*)d_in[0];
    const int*   ei    = (const int*)d_in[1];
    const int*   batch = (const int*)d_in[2];
    const float* W1 = (const float*)d_in[3];
    const float* b1 = (const float*)d_in[4];
    const float* W2 = (const float*)d_in[5];
    const float* b2 = (const float*)d_in[6];
    const float* W3 = (const float*)d_in[7];
    const float* b3 = (const float*)d_in[8];
    const float* fw1 = (const float*)d_in[9];
    const float* fb1 = (const float*)d_in[10];
    const float* fw2 = (const float*)d_in[11];
    const float* fb2 = (const float*)d_in[12];
    float* out = (float*)d_out;

    const int* src = ei;
    const int* dst = ei + N_EDGES;

    // workspace layout (~81 MB)
    char* p = (char*)d_ws;
    float*  dinv  = (float*)p;  p += 100352 * 4;
    int*    cur   = (int*)p;    p += 100352 * 4;
    int*    csr   = (int*)p;    p += (size_t)N_NODES * PAD * 4;
    ushort* img1  = (ushort*)p; p += 128 * 128 * 2;   // W1 LDS image (32KB)
    ushort* img2  = (ushort*)p; p += 256 * 128 * 2;   // W2 LDS image (64KB)
    ushort* img3  = (ushort*)p; p += 128 * 256 * 2;   // W3 LDS image (64KB)
    ushort* xb    = (ushort*)p; p += (size_t)(N_NODES + 1) * 80 * 2;
    ushort* buf1  = (ushort*)p; p += (size_t)(N_NODES + 1) * 128 * 2;
    ushort* buf3  = (ushort*)p; p += (size_t)(N_NODES + 1) * 128 * 2;

    const int T = 256;

    // setup, CSR fill, dinv, x->bf16 pre-scaled
    setup_k<<<(N_NODES * PAD / 4 + T - 1) / T, T, 0, stream>>>(cur, (int4*)csr, xb, buf1, buf3);
    fill_csr_k<<<(N_EDGES + T - 1) / T, T, 0, stream>>>(src, dst, cur, csr);
    dinv_k<<<(N_NODES + T - 1) / T, T, 0, stream>>>(cur, dinv, N_NODES);
    x2bf_k<<<(N_NODES * 80 + T - 1) / T, T, 0, stream>>>(x, dinv, xb);

    // weight image preps
    prep_w1img_k<<<(128 * 128 + T - 1) / T, T, 0, stream>>>(W1, img1);
    prep_w2img_k<<<(256 * 128 + T - 1) / T, T, 0, stream>>>(W2, img2);
    prep_w3img_k<<<(128 * 256 + T - 1) / T, T, 0, stream>>>(W3, img3);

    // layer 1: fused gather + GEMM -> buf1 (pre-scaled bf16)
    gemm1g_k<<<782, 512, 0, stream>>>(xb, cur, csr, dinv, img1, b1, buf1, N_NODES);

    // layers 2+3: fused gather + double GEMM -> buf3 (pre-scaled bf16)
    gemm23g_k<<<782, 512, 0, stream>>>(buf1, cur, csr, dinv, img2, b2, img3, buf3, N_NODES);

    // layer-3 gather + mean-pool + MLP head
    pool_head_k<<<N_GRAPHS, 512, 0, stream>>>(buf3, cur, csr, dinv, b3, batch,
                                              fw1, fb1, fw2, fb2, out);
}

// Round 14
// 303.477 us; speedup vs baseline: 1.0657x; 1.0657x over previous
//
#include <hip/hip_runtime.h>

#define N_NODES 100000
#define N_EDGES 400000
#define N_GRAPHS 2000
#define NODE_F 78
#define HID 128
#define PAD 32
#define SENT N_NODES   // sentinel row index (zeroed row appended to gathered buffers)

typedef __attribute__((ext_vector_type(8))) short short8v;
typedef __attribute__((ext_vector_type(4))) float f32x4;

__device__ __forceinline__ ushort f2bf(float f) {
    unsigned u = __float_as_uint(f);
    unsigned r = (u + 0x7FFFu + ((u >> 16) & 1u)) >> 16;  // round-to-nearest-even
    return (ushort)r;
}
__device__ __forceinline__ float bf2f(ushort b) {
    return __uint_as_float(((unsigned)b) << 16);
}
__device__ __forceinline__ float2 bfx2(const ushort* p) {
    unsigned u = *reinterpret_cast<const unsigned*>(p);
    return make_float2(__uint_as_float(u << 16), __uint_as_float(u & 0xffff0000u));
}
__device__ __forceinline__ unsigned packbf(float a, float b) {
    return (unsigned)f2bf(a) | ((unsigned)f2bf(b) << 16);
}
// async global->LDS, 16B per lane; lds base wave-uniform, gsrc per-lane
__device__ __forceinline__ void gload16(const ushort* g, ushort* l) {
    __builtin_amdgcn_global_load_lds((const __attribute__((address_space(1))) unsigned int*)g,
                                     (__attribute__((address_space(3))) unsigned int*)l, 16, 0, 0);
}

// ---------------- setup: zero cursor + sentinel rows (CSR sentinel-pad happens post-fill) ----------------

__global__ void setup_k(int* __restrict__ cursor, ushort* __restrict__ xb,
                        ushort* __restrict__ b1, ushort* __restrict__ b3) {
    int i = blockIdx.x * blockDim.x + threadIdx.x;
    if (i < N_NODES) cursor[i] = 0;
    if (i < 80) xb[(size_t)N_NODES * 80 + i] = 0;
    if (i < 128) {
        b1[(size_t)N_NODES * 128 + i] = 0;
        b3[(size_t)N_NODES * 128 + i] = 0;
    }
}

__global__ void fill_csr_k(const int* __restrict__ src, const int* __restrict__ dst,
                           int* __restrict__ cursor, int* __restrict__ csr) {
    int e = blockIdx.x * blockDim.x + threadIdx.x;
    if (e >= N_EDGES) return;
    int s = src[e], d = dst[e];
    int p = atomicAdd(&cursor[d], 1);
    if (p < PAD) csr[d * PAD + p] = s;
}

// sentinel-pad slots deg..ceil8(deg)-1 (the only slots the 8-batched gathers read past deg)
__global__ void pad_csr_k(const int* __restrict__ cursor, int* __restrict__ csr) {
    int i = blockIdx.x * blockDim.x + threadIdx.x;
    if (i >= N_NODES) return;
    int d = cursor[i]; if (d > PAD) d = PAD;
    int e = (d + 7) & ~7;
    for (int p = d; p < e; ++p) csr[i * PAD + p] = SENT;
}

__global__ void dinv_k(const int* __restrict__ deg, float* __restrict__ dinv, int n) {
    int i = blockIdx.x * blockDim.x + threadIdx.x;
    if (i < n) dinv[i] = rsqrtf((float)deg[i] + 1.0f);
}

// ---------------- x -> bf16 pre-scaled by dinv[row], padded to 80 cols ----------------

__global__ void x2bf_k(const float* __restrict__ x, const float* __restrict__ dinv,
                       ushort* __restrict__ xb) {
    int idx = blockIdx.x * blockDim.x + threadIdx.x;
    if (idx >= N_NODES * 80) return;
    int n = idx / 80, f = idx - n * 80;
    xb[idx] = (f < NODE_F) ? f2bf(x[(long long)n * NODE_F + f] * dinv[n]) : (ushort)0;
}

// ---------------- all weight preps in one kernel ----------------
// W1 [80k][128n] -> bf16 [n][256] zero-padded (gemm1 layout)
// W2 [128k][256n] -> image: 4 quarter-tiles (64n x 128k, 16KB), chunk-swizzled
// W3 [256k][128n] -> image: 4 k-chunk tiles (128n x 64k, 16KB), chunk-swizzled

__global__ void prep_all_k(const float* __restrict__ W1, const float* __restrict__ W2,
                           const float* __restrict__ W3, ushort* __restrict__ w1h,
                           ushort* __restrict__ img2, ushort* __restrict__ img3) {
    int idx = blockIdx.x * blockDim.x + threadIdx.x;
    if (idx < 128 * 256) {
        int n = idx >> 8, k = idx & 255;
        w1h[idx] = (k < NODE_F) ? f2bf(W1[(long long)k * 128 + n]) : (ushort)0;
    } else if (idx < 128 * 256 + 256 * 128) {
        int t = idx - 128 * 256;
        int n = t >> 7, k = t & 127;
        int c = k >> 3;
        int slot = (c & 8) | ((c & 7) ^ (n & 7));
        img2[n * 128 + slot * 8 + (k & 7)] = f2bf(W2[(long long)k * 256 + n]);
    } else if (idx < 128 * 256 + 256 * 128 + 128 * 256) {
        int t = idx - 128 * 256 - 256 * 128;
        int n = t >> 8, k = t & 255;
        int ch = k >> 6, cc = (k >> 3) & 7;
        img3[ch * 8192 + n * 64 + ((cc ^ (n & 7)) * 8) + (k & 7)] = f2bf(W3[(long long)k * 128 + n]);
    }
}

// ---------------- layer-1 GEMM: C_bf16 = relu(A_bf16[M,80] @ W1 + b1) * dinv[row] ----------------

__global__ __launch_bounds__(256) void gemm1_k(
        const ushort* __restrict__ A, int M,
        const ushort* __restrict__ Wth, const float* __restrict__ bias,
        const float* __restrict__ dinv, ushort* __restrict__ C) {
    __shared__ ushort At[128 * 64];
    __shared__ ushort Bh[128 * 64];
    const int tid = threadIdx.x;
    const int w = tid >> 6, l = tid & 63;
    const int bm = blockIdx.x * 128;

    f32x4 acc[2][8];
    #pragma unroll
    for (int m = 0; m < 2; ++m)
        #pragma unroll
        for (int j = 0; j < 8; ++j)
            acc[m][j] = (f32x4){0.f, 0.f, 0.f, 0.f};

    for (int k0 = 0; k0 < 128; k0 += 64) {
        __syncthreads();
        #pragma unroll
        for (int i = 0; i < 4; ++i) {
            int idx = tid + i * 256;
            int r = idx >> 3, s0 = idx & 7;
            int gr = bm + r; if (gr >= M) gr = M - 1;
            int kk = k0 + s0 * 8;
            short8v v;
            if (kk < 80) v = *reinterpret_cast<const short8v*>(&A[(size_t)gr * 80 + kk]);
            else v = (short8v){0,0,0,0,0,0,0,0};
            *reinterpret_cast<short8v*>(&At[r * 64 + (s0 ^ (r & 7)) * 8]) = v;
        }
        #pragma unroll
        for (int i = 0; i < 4; ++i) {
            int idx = tid + i * 256;
            int n = idx >> 3, s0 = idx & 7;
            long long g = (long long)n * 256 + k0 + s0 * 8;
            *reinterpret_cast<short8v*>(&Bh[n * 64 + (s0 ^ (n & 7)) * 8]) =
                *reinterpret_cast<const short8v*>(&Wth[g]);
        }
        __syncthreads();
        #pragma unroll
        for (int ks = 0; ks < 2; ++ks) {
            short8v ah[2];
            #pragma unroll
            for (int m = 0; m < 2; ++m) {
                int r = w * 32 + m * 16 + (l & 15);
                ah[m] = *reinterpret_cast<const short8v*>(
                    &At[r * 64 + ((ks * 4 + (l >> 4)) ^ (r & 7)) * 8]);
            }
            #pragma unroll
            for (int j = 0; j < 8; ++j) {
                int n = j * 16 + (l & 15);
                short8v bh = *reinterpret_cast<const short8v*>(
                    &Bh[n * 64 + ((ks * 4 + (l >> 4)) ^ (n & 7)) * 8]);
                #pragma unroll
                for (int m = 0; m < 2; ++m)
                    acc[m][j] = __builtin_amdgcn_mfma_f32_16x16x32_bf16(ah[m], bh, acc[m][j], 0, 0, 0);
            }
        }
    }

    float dv[2][4];
    #pragma unroll
    for (int m = 0; m < 2; ++m)
        #pragma unroll
        for (int rg = 0; rg < 4; ++rg) {
            int gr = bm + w * 32 + m * 16 + (l >> 4) * 4 + rg;
            dv[m][rg] = (gr < M) ? dinv[gr] : 0.f;
        }
    #pragma unroll
    for (int j = 0; j < 8; ++j) {
        int gc = j * 16 + (l & 15);
        float bv = bias[gc];
        #pragma unroll
        for (int m = 0; m < 2; ++m) {
            #pragma unroll
            for (int rg = 0; rg < 4; ++rg) {
                int gr = bm + w * 32 + m * 16 + (l >> 4) * 4 + rg;
                if (gr < M)
                    C[(size_t)gr * 128 + gc] = f2bf(fmaxf(acc[m][j][rg] + bv, 0.0f) * dv[m][rg]);
            }
        }
    }
}

// ---------------- fused layer2+layer3 GEMM v3: DMA staging + dbuf weights + per-wave T ----------------

__global__ __launch_bounds__(512) void gemm23_k(
        const ushort* __restrict__ A,    // [M,128] bf16 rows, pre-swizzled 16B chunks
        const ushort* __restrict__ W2i, const float* __restrict__ b2,
        const ushort* __restrict__ W3i, const float* __restrict__ dinv,
        ushort* __restrict__ C, int M) {
    __shared__ ushort At[128 * 128];     // 32KB
    __shared__ ushort Wb[2][8192];       // 2x16KB
    __shared__ ushort Tb[8][1024];       // 8x2KB, per-wave
    const int tid = threadIdx.x;
    const int w = tid >> 6, l = tid & 63;
    const int bm = blockIdx.x * 128;

    {
        const ushort* asrc = A + (size_t)bm * 128;
        #pragma unroll
        for (int i = 0; i < 4; ++i) {
            int chunk = w * 4 + i;
            gload16(asrc + chunk * 512 + l * 8, &At[chunk * 512]);
        }
        #pragma unroll
        for (int i = 0; i < 2; ++i) {
            int chunk = w * 2 + i;
            gload16(W2i + chunk * 512 + l * 8, &Wb[0][chunk * 512]);
        }
    }
    __syncthreads();

    f32x4 acc2[16];
    #pragma unroll
    for (int j = 0; j < 16; ++j) acc2[j] = (f32x4){0.f, 0.f, 0.f, 0.f};

    #pragma unroll
    for (int q = 0; q < 4; ++q) {
        const ushort* nsrc = (q < 3) ? (W2i + (q + 1) * 8192) : W3i;
        #pragma unroll
        for (int i = 0; i < 2; ++i) {
            int chunk = w * 2 + i;
            gload16(nsrc + chunk * 512 + l * 8, &Wb[(q + 1) & 1][chunk * 512]);
        }
        const ushort* wb = Wb[q & 1];
        #pragma unroll
        for (int ks = 0; ks < 4; ++ks) {
            int r = w * 16 + (l & 15);
            int ck = ks * 4 + (l >> 4);
            int sa = (ck & 8) | ((ck & 7) ^ (r & 7));
            short8v ah = *reinterpret_cast<const short8v*>(&At[r * 128 + sa * 8]);
            #pragma unroll
            for (int jt = 0; jt < 4; ++jt) {
                int n = jt * 16 + (l & 15);
                int sb = (ck & 8) | ((ck & 7) ^ (n & 7));
                short8v bh = *reinterpret_cast<const short8v*>(&wb[n * 128 + sb * 8]);
                acc2[q * 4 + jt] = __builtin_amdgcn_mfma_f32_16x16x32_bf16(ah, bh, acc2[q * 4 + jt], 0, 0, 0);
            }
        }
        __syncthreads();
    }

    f32x4 acc3[8];
    #pragma unroll
    for (int j = 0; j < 8; ++j) acc3[j] = (f32x4){0.f, 0.f, 0.f, 0.f};

    #pragma unroll
    for (int ch = 0; ch < 4; ++ch) {
        if (ch < 3) {
            const ushort* nsrc = W3i + (ch + 1) * 8192;
            #pragma unroll
            for (int i = 0; i < 2; ++i) {
                int chunk = w * 2 + i;
                gload16(nsrc + chunk * 512 + l * 8, &Wb[(ch + 1) & 1][chunk * 512]);
            }
        }
        #pragma unroll
        for (int jj = 0; jj < 4; ++jj) {
            int j = ch * 4 + jj;
            float bv = b2[ch * 64 + jj * 16 + (l & 15)];
            #pragma unroll
            for (int rg = 0; rg < 4; ++rg) {
                int rr = (l >> 4) * 4 + rg;
                int cl = jj * 16 + (l & 15);
                Tb[w][rr * 64 + (((cl >> 3) ^ (rr & 7)) * 8) + (cl & 7)] =
                    f2bf(fmaxf(acc2[j][rg] + bv, 0.f));
            }
        }
        const ushort* wb = Wb[ch & 1];
        #pragma unroll
        for (int ks = 0; ks < 2; ++ks) {
            int rt = l & 15;
            int ck = ks * 4 + (l >> 4);
            short8v ah = *reinterpret_cast<const short8v*>(&Tb[w][rt * 64 + ((ck ^ (rt & 7)) * 8)]);
            #pragma unroll
            for (int j3 = 0; j3 < 8; ++j3) {
                int n = j3 * 16 + (l & 15);
                short8v bh = *reinterpret_cast<const short8v*>(&wb[n * 64 + ((ck ^ (n & 7)) * 8)]);
                acc3[j3] = __builtin_amdgcn_mfma_f32_16x16x32_bf16(ah, bh, acc3[j3], 0, 0, 0);
            }
        }
        __syncthreads();
    }

    float dv[4];
    #pragma unroll
    for (int rg = 0; rg < 4; ++rg) {
        int gr = bm + w * 16 + (l >> 4) * 4 + rg;
        dv[rg] = (gr < M) ? dinv[gr] : 0.f;
    }
    #pragma unroll
    for (int j = 0; j < 8; ++j) {
        int gc = j * 16 + (l & 15);
        #pragma unroll
        for (int rg = 0; rg < 4; ++rg) {
            int gr = bm + w * 16 + (l >> 4) * 4 + rg;
            if (gr < M) C[(size_t)gr * 128 + gc] = f2bf(acc3[j][rg] * dv[rg]);
        }
    }
}

// ---------------- gathers: pure row sums, bf16 in/out, 8-edge batched ----------------

// out[i] = bf16( dinv[i] * sum rows ), [N,80] (normal layout, feeds gemm1)
__global__ __launch_bounds__(256) void gather78_k(const ushort* __restrict__ Xb,
        const int* __restrict__ deg, const int* __restrict__ csr,
        const float* __restrict__ dinv, ushort* __restrict__ out) {
    int wid = (blockIdx.x * blockDim.x + threadIdx.x) >> 6;
    int lane = threadIdx.x & 63;
    if (wid >= N_NODES) return;
    float di = dinv[wid];
    float ax = 0.f, ay = 0.f;
    bool act = lane < 40;
    if (act) {
        float2 v = bfx2(&Xb[(size_t)wid * 80 + lane * 2]);
        ax = v.x; ay = v.y;
    }
    int d = deg[wid]; if (d > PAD) d = PAD;
    const int4* e4 = reinterpret_cast<const int4*>(csr + wid * PAD);
    for (int j0 = 0; j0 < d; j0 += 8) {
        int4 e0 = e4[j0 >> 2];
        int4 e1 = e4[(j0 >> 2) + 1];
        if (act) {
            float2 v0 = bfx2(&Xb[(size_t)e0.x * 80 + lane * 2]);
            float2 v1 = bfx2(&Xb[(size_t)e0.y * 80 + lane * 2]);
            float2 v2 = bfx2(&Xb[(size_t)e0.z * 80 + lane * 2]);
            float2 v3 = bfx2(&Xb[(size_t)e0.w * 80 + lane * 2]);
            float2 v4 = bfx2(&Xb[(size_t)e1.x * 80 + lane * 2]);
            float2 v5 = bfx2(&Xb[(size_t)e1.y * 80 + lane * 2]);
            float2 v6 = bfx2(&Xb[(size_t)e1.z * 80 + lane * 2]);
            float2 v7 = bfx2(&Xb[(size_t)e1.w * 80 + lane * 2]);
            ax += (v0.x + v1.x) + (v2.x + v3.x) + (v4.x + v5.x) + (v6.x + v7.x);
            ay += (v0.y + v1.y) + (v2.y + v3.y) + (v4.y + v5.y) + (v6.y + v7.y);
        }
    }
    if (act)
        *reinterpret_cast<unsigned*>(&out[(size_t)wid * 80 + lane * 2]) = packbf(ax * di, ay * di);
}

// out[i] = bf16( dinv[i] * sum rows ), [N,128], rows PRE-SWIZZLED for gemm23 DMA staging
__global__ __launch_bounds__(256) void gather128_k(const ushort* __restrict__ A,
        const int* __restrict__ deg, const int* __restrict__ csr,
        const float* __restrict__ dinv, ushort* __restrict__ out) {
    int wid = (blockIdx.x * blockDim.x + threadIdx.x) >> 6;
    int lane = threadIdx.x & 63;
    if (wid >= N_NODES) return;
    float di = dinv[wid];
    float2 v = bfx2(&A[(size_t)wid * 128 + lane * 2]);
    float ax = v.x, ay = v.y;
    int d = deg[wid]; if (d > PAD) d = PAD;
    const int4* e4 = reinterpret_cast<const int4*>(csr + wid * PAD);
    for (int j0 = 0; j0 < d; j0 += 8) {
        int4 e0 = e4[j0 >> 2];
        int4 e1 = e4[(j0 >> 2) + 1];
        float2 w0 = bfx2(&A[(size_t)e0.x * 128 + lane * 2]);
        float2 w1 = bfx2(&A[(size_t)e0.y * 128 + lane * 2]);
        float2 w2 = bfx2(&A[(size_t)e0.z * 128 + lane * 2]);
        float2 w3 = bfx2(&A[(size_t)e0.w * 128 + lane * 2]);
        float2 w4 = bfx2(&A[(size_t)e1.x * 128 + lane * 2]);
        float2 w5 = bfx2(&A[(size_t)e1.y * 128 + lane * 2]);
        float2 w6 = bfx2(&A[(size_t)e1.z * 128 + lane * 2]);
        float2 w7 = bfx2(&A[(size_t)e1.w * 128 + lane * 2]);
        ax += (w0.x + w1.x) + (w2.x + w3.x) + (w4.x + w5.x) + (w6.x + w7.x);
        ay += (w0.y + w1.y) + (w2.y + w3.y) + (w4.y + w5.y) + (w6.y + w7.y);
    }
    int kt = lane >> 5, cc = (lane >> 2) & 7, q4 = lane & 3;
    int slot = kt * 8 + (cc ^ (wid & 7));
    *reinterpret_cast<unsigned*>(&out[(size_t)wid * 128 + slot * 8 + q4 * 2]) = packbf(ax * di, ay * di);
}

// ---------------- fused layer-3 gather + mean-pool + MLP head (8 waves/graph) ----------------

__global__ __launch_bounds__(512) void pool_head_k(
        const ushort* __restrict__ A,      // [N,128] bf16, pre-scaled, normal layout
        const int* __restrict__ deg, const int* __restrict__ csr,
        const float* __restrict__ dinv, const float* __restrict__ b3,
        const int* __restrict__ batch,
        const float* __restrict__ fw1, const float* __restrict__ fb1,
        const float* __restrict__ fw2, const float* __restrict__ fb2,
        float* __restrict__ out) {
    __shared__ float part[8][HID];
    __shared__ float ps[HID];
    const int g = blockIdx.x;
    const int w = threadIdx.x >> 6, lane = threadIdx.x & 63;

    int start, end;
    {
        int l = 0, h = N_NODES;
        while (l < h) { int m = (l + h) >> 1; if (batch[m] < g) l = m + 1; else h = m; }
        start = l;
        h = N_NODES;
        while (l < h) { int m = (l + h) >> 1; if (batch[m] < g + 1) l = m + 1; else h = m; }
        end = l;
    }

    float sx = 0.f, sy = 0.f;
    const float bx = b3[lane * 2], by = b3[lane * 2 + 1];
    for (int i = start + w; i < end; i += 8) {
        float di = dinv[i];
        float2 v = bfx2(&A[(size_t)i * 128 + lane * 2]);
        float ax = v.x, ay = v.y;
        int d = deg[i]; if (d > PAD) d = PAD;
        const int4* e4 = reinterpret_cast<const int4*>(csr + i * PAD);
        for (int j0 = 0; j0 < d; j0 += 8) {
            int4 e0 = e4[j0 >> 2];
            int4 e1 = e4[(j0 >> 2) + 1];
            float2 w0 = bfx2(&A[(size_t)e0.x * 128 + lane * 2]);
            float2 w1 = bfx2(&A[(size_t)e0.y * 128 + lane * 2]);
            float2 w2 = bfx2(&A[(size_t)e0.z * 128 + lane * 2]);
            float2 w3 = bfx2(&A[(size_t)e0.w * 128 + lane * 2]);
            float2 w4 = bfx2(&A[(size_t)e1.x * 128 + lane * 2]);
            float2 w5 = bfx2(&A[(size_t)e1.y * 128 + lane * 2]);
            float2 w6 = bfx2(&A[(size_t)e1.z * 128 + lane * 2]);
            float2 w7 = bfx2(&A[(size_t)e1.w * 128 + lane * 2]);
            ax += (w0.x + w1.x) + (w2.x + w3.x) + (w4.x + w5.x) + (w6.x + w7.x);
            ay += (w0.y + w1.y) + (w2.y + w3.y) + (w4.y + w5.y) + (w6.y + w7.y);
        }
        sx += fmaxf(ax * di + bx, 0.f);
        sy += fmaxf(ay * di + by, 0.f);
    }
    part[w][lane * 2] = sx;
    part[w][lane * 2 + 1] = sy;
    __syncthreads();

    if (w == 0) {
        float inv = (end > start) ? 1.0f / (float)(end - start) : 0.0f;
        float s0 = 0.f, s1 = 0.f;
        #pragma unroll
        for (int q = 0; q < 8; ++q) {
            s0 += part[q][lane * 2];
            s1 += part[q][lane * 2 + 1];
        }
        ps[lane * 2] = s0 * inv;
        ps[lane * 2 + 1] = s1 * inv;
    }
    __syncthreads();

    if (w == 0) {
        float acc = fb1[lane];
        #pragma unroll 8
        for (int k = 0; k < HID; ++k) acc = fmaf(ps[k], fw1[k * 64 + lane], acc);
        float v = fmaxf(acc, 0.0f) * fw2[lane];
        #pragma unroll
        for (int off = 32; off > 0; off >>= 1) v += __shfl_down(v, off);
        if (lane == 0) out[g] = v + fb2[0];
    }
}

// ---------------- launch ----------------

extern "C" void kernel_launch(void* const* d_in, const int* in_sizes, int n_in,
                              void* d_out, int out_size, void* d_ws, size_t ws_size,
                              hipStream_t stream) {
    const float* x     = (const float*)d_in[0];
    const int*   ei    = (const int*)d_in[1];
    const int*   batch = (const int*)d_in[2];
    const float* W1 = (const float*)d_in[3];
    const float* b1 = (const float*)d_in[4];
    const float* W2 = (const float*)d_in[5];
    const float* b2 = (const float*)d_in[6];
    const float* W3 = (const float*)d_in[7];
    const float* b3 = (const float*)d_in[8];
    const float* fw1 = (const float*)d_in[9];
    const float* fb1 = (const float*)d_in[10];
    const float* fw2 = (const float*)d_in[11];
    const float* fb2 = (const float*)d_in[12];
    float* out = (float*)d_out;

    const int* src = ei;
    const int* dst = ei + N_EDGES;

    // workspace layout (~120 MB)
    char* p = (char*)d_ws;
    float*  dinv  = (float*)p;  p += 100352 * 4;
    int*    cur   = (int*)p;    p += 100352 * 4;
    int*    csr   = (int*)p;    p += (size_t)N_NODES * PAD * 4;
    ushort* w1h   = (ushort*)p; p += 256 * 256 * 2;
    ushort* img2  = (ushort*)p; p += 256 * 128 * 2;   // W2 LDS image (64KB)
    ushort* img3  = (ushort*)p; p += 128 * 256 * 2;   // W3 LDS image (64KB)
    ushort* xb    = (ushort*)p; p += (size_t)(N_NODES + 1) * 80 * 2;
    ushort* xpadb = (ushort*)p; p += (size_t)N_NODES * 80 * 2;
    ushort* buf1  = (ushort*)p; p += (size_t)(N_NODES + 1) * 128 * 2;
    ushort* buf2  = (ushort*)p; p += (size_t)N_NODES * 128 * 2;   // pre-swizzled rows
    ushort* buf3  = (ushort*)p; p += (size_t)(N_NODES + 1) * 128 * 2;

    const int T = 256;
    const int gw = (N_NODES * 64 + T - 1) / T;  // one wave per node

    // setup, CSR fill + sentinel pad, dinv, x->bf16 pre-scaled, weight preps
    setup_k<<<(N_NODES + T - 1) / T, T, 0, stream>>>(cur, xb, buf1, buf3);
    fill_csr_k<<<(N_EDGES + T - 1) / T, T, 0, stream>>>(src, dst, cur, csr);
    pad_csr_k<<<(N_NODES + T - 1) / T, T, 0, stream>>>(cur, csr);
    dinv_k<<<(N_NODES + T - 1) / T, T, 0, stream>>>(cur, dinv, N_NODES);
    x2bf_k<<<(N_NODES * 80 + T - 1) / T, T, 0, stream>>>(x, dinv, xb);
    prep_all_k<<<(128 * 256 + 256 * 128 + 128 * 256 + T - 1) / T, T, 0, stream>>>(
        W1, W2, W3, w1h, img2, img3);

    // layer 1
    gather78_k<<<gw, T, 0, stream>>>(xb, cur, csr, dinv, xpadb);
    gemm1_k<<<782, 256, 0, stream>>>(xpadb, N_NODES, w1h, b1, dinv, buf1);

    // layer 2 gather (swizzled write), fused L2+L3 GEMM v3
    gather128_k<<<gw, T, 0, stream>>>(buf1, cur, csr, dinv, buf2);
    gemm23_k<<<782, 512, 0, stream>>>(buf2, img2, b2, img3, dinv, buf3, N_NODES);

    // layer-3 gather + mean-pool + MLP head
    pool_head_k<<<N_GRAPHS, 512, 0, stream>>>(buf3, cur, csr, dinv, b3, batch,
                                              fw1, fb1, fw2, fb2, out);
}